// Round 7
// baseline (3624.330 us; speedup 1.0000x reference)
//
#include <hip/hip_runtime.h>
#include <hip/hip_cooperative_groups.h>

#define N_NODES 10242
#define NNZ_E   71694
#define NNZ_PAD_MAX (NNZ_E + 3 * N_NODES)   // rows padded to multiple of 4
#define BT      32      // B*T
#define C_IN    16
#define K_S     20
#define C_OUT   32
#define F       512     // BT * C_IN
typedef unsigned short u16;
typedef unsigned int   u32;

#define SLICE_FLOATS ((size_t)N_NODES * 64)  // one 64-col slice of a T buffer
#define BUF_FLOATS   ((size_t)N_NODES * F)   // fp32 T buffer, sliced layout [8][N][64]
#define BUF_BYTES    (BUF_FLOATS * 4)        // ~21 MB
#define PROJ_ELEMS   ((size_t)N_NODES * F)   // bf16 proj copy, layout [n][bt*16+c]
#define PROJ_BYTES   (PROJ_ELEMS * 2)        // ~10.5 MB
#define GRID_BLKS    1024                    // 4 blocks/CU, co-resident (coop launch)
#define MAX_CHUNKS   24

typedef __attribute__((ext_vector_type(8)))  short short8;
typedef __attribute__((ext_vector_type(16))) float float16;

__device__ __forceinline__ u16 f2bf(float f) {
    union { float f; u32 u; } v; v.f = f;
    u32 r = v.u + 0x7fffu + ((v.u >> 16) & 1u);   // RNE
    return (u16)(r >> 16);
}

// ---------------- CSR build (deterministic, rows padded to x4) -------------

__global__ void zero_kernel(int* p, int n) {
    int i = blockIdx.x * blockDim.x + threadIdx.x;
    if (i < n) p[i] = 0;
}

__global__ void count_kernel(const int* __restrict__ erow, int* cnt) {
    int e = blockIdx.x * blockDim.x + threadIdx.x;
    if (e < NNZ_E) atomicAdd(&cnt[erow[e]], 1);
}

__global__ void scan_kernel(const int* __restrict__ cnt, int* row_ptr, int* cursor) {
    const int T = 256;
    const int chunk = (N_NODES + T - 1) / T;  // 41
    __shared__ int part[T];
    int t = threadIdx.x;
    int base = t * chunk;
    int s = 0;
    for (int i = 0; i < chunk; ++i) {
        int idx = base + i;
        if (idx < N_NODES) s += (cnt[idx] + 3) & ~3;
    }
    part[t] = s;
    __syncthreads();
    for (int off = 1; off < T; off <<= 1) {
        int v = (t >= off) ? part[t - off] : 0;
        __syncthreads();
        part[t] += v;
        __syncthreads();
    }
    int run = (t == 0) ? 0 : part[t - 1];
    for (int i = 0; i < chunk; ++i) {
        int idx = base + i;
        if (idx < N_NODES) {
            row_ptr[idx] = run;
            cursor[idx]  = run;
            run += (cnt[idx] + 3) & ~3;
        }
    }
    if (base <= N_NODES && N_NODES < base + chunk) {
        row_ptr[N_NODES] = run;
    }
}

__global__ void scatter_kernel(const int* __restrict__ erow, int* cursor, int* __restrict__ eidx) {
    int e = blockIdx.x * blockDim.x + threadIdx.x;
    if (e < NNZ_E) {
        int p = atomicAdd(&cursor[erow[e]], 1);
        eidx[p] = e;
    }
}

__global__ void sort_rows_kernel(const int* __restrict__ row_ptr, const int* __restrict__ cnt,
                                 int* eidx) {
    int r = blockIdx.x * blockDim.x + threadIdx.x;
    if (r >= N_NODES) return;
    int s = row_ptr[r], e = s + cnt[r];
    for (int i = s + 1; i < e; ++i) {
        int key = eidx[i];
        int j = i - 1;
        while (j >= s && eidx[j] > key) { eidx[j + 1] = eidx[j]; --j; }
        eidx[j + 1] = key;
    }
}

__global__ void fill_csr_kernel(const int* __restrict__ row_ptr, const int* __restrict__ cnt,
                                const int* __restrict__ eidx,
                                const int* __restrict__ ecol, const float* __restrict__ eval,
                                int2* __restrict__ cpack) {
    int r = blockIdx.x * blockDim.x + threadIdx.x;
    if (r >= N_NODES) return;
    int s = row_ptr[r], e = s + cnt[r];
    for (int p = s; p < e; ++p) {
        int ed = eidx[p];
        cpack[p] = make_int2(ecol[ed], __float_as_int(eval[ed]));
    }
}

// B-fragments for v_mfma_f32_32x32x16_bf16 (verified layout, round 6):
// lane L, reg j -> B[k=8*(L>>5)+j][col=L&31] = W[cout=col][c=k][k_cheb]
__global__ void wtfrag_kernel(const float* __restrict__ W, u16* __restrict__ wtfrag) {
    int i = blockIdx.x * blockDim.x + threadIdx.x;  // K_S*64*8 = 10240
    if (i >= K_S * 64 * 8) return;
    int j    = i & 7;
    int lane = (i >> 3) & 63;
    int k    = i >> 9;
    int cout = lane & 31;
    int c    = ((lane >> 5) << 3) + j;
    wtfrag[i] = f2bf(W[cout * (C_IN * K_S) + c * K_S + k]);
}

// ---------------- transform: x -> T0 (fp32 sliced) + bf16 proj slot 0 ------
// fp32 sliced layout: T[s][n][lane], global column j = s*64+lane = bt*16+c

__global__ __launch_bounds__(256) void transform_kernel(
        const float* __restrict__ x, float* __restrict__ T0, u16* __restrict__ proj0) {
    int g = blockIdx.x * 256 + threadIdx.x;   // over N*F
    int n    = g >> 9;
    int rem  = g & 511;
    int s    = rem >> 6;
    int lane = rem & 63;
    int bt   = rem >> 4;
    int c    = rem & 15;
    float v = x[((size_t)bt * N_NODES + n) * C_IN + c];
    T0[(size_t)s * SLICE_FLOATS + (size_t)n * 64 + lane] = v;
    proj0[(size_t)n * F + rem] = f2bf(v);
}

// ---------------- persistent cooperative Chebyshev kernel ------------------
// Each block reads its hardware XCC id; blocks on XCD s evolve column-slice s
// (2.6 MB, fits that XCD's 4 MB L2) for all steps [kb, ke). grid.sync between
// steps. Census-based ranking: 1 atomic per block, zero per-work claims.
// Fallback (any XCD with 0 blocks): slice = blockIdx%8 — correct, slower.

__global__ __launch_bounds__(256, 4) void cheb_coop_kernel(
        float* __restrict__ ring, u16* __restrict__ projbase, int Rbf,
        const int* __restrict__ row_ptr, const int2* __restrict__ cpack,
        int* __restrict__ census, int kb, int ke) {
    cooperative_groups::grid_group grid = cooperative_groups::this_grid();

    int xcc;
    asm volatile("s_getreg_b32 %0, hwreg(HW_REG_XCC_ID)" : "=s"(xcc));
    xcc &= 7;
    __shared__ int sh_rank;
    if (threadIdx.x == 0) sh_rank = atomicAdd(&census[xcc], 1);
    __syncthreads();
    int myrank = sh_rank;
    grid.sync();

    bool ok = true;
    #pragma unroll
    for (int s = 0; s < 8; ++s) ok = ok && (census[s] > 0);
    int slice, rank, nb;
    if (ok) { slice = xcc;            rank = myrank;          nb = census[xcc]; }
    else    { slice = blockIdx.x & 7; rank = blockIdx.x >> 3; nb = gridDim.x >> 3; }

    int wave = threadIdx.x >> 6;
    int lane = threadIdx.x & 63;
    int wr = rank * 4 + wave;     // wave rank within slice
    int W  = nb * 4;              // waves in slice

    for (int k = kb; k < ke; ++k) {
        const float* sB = ring + (size_t)((k - 1) % 3) * BUF_FLOATS + (size_t)slice * SLICE_FLOATS;
        const float* sA = ring + (size_t)((k + 1) % 3) * BUF_FLOATS + (size_t)slice * SLICE_FLOATS;
        float*       dp = ring + (size_t)(k % 3) * BUF_FLOATS + (size_t)slice * SLICE_FLOATS;
        u16*         pw = projbase + (size_t)(k % Rbf) * PROJ_ELEMS + slice * 64;
        float alpha = (k == 1) ? 1.f : 2.f;
        bool has_beta = (k >= 2);

        for (int n = wr; n < N_NODES; n += W) {
            int es = row_ptr[n], ee = row_ptr[n + 1];   // padded to multiple of 4
            float a0 = 0.f, a1 = 0.f, a2 = 0.f, a3 = 0.f;
            for (int e = es; e < ee; e += 4) {
                int2 p0 = cpack[e],     p1 = cpack[e + 1];
                int2 p2 = cpack[e + 2], p3 = cpack[e + 3];
                a0 += __int_as_float(p0.y) * sB[p0.x * 64 + lane];
                a1 += __int_as_float(p1.y) * sB[p1.x * 64 + lane];
                a2 += __int_as_float(p2.y) * sB[p2.x * 64 + lane];
                a3 += __int_as_float(p3.y) * sB[p3.x * 64 + lane];
            }
            float y = alpha * ((a0 + a1) + (a2 + a3));
            if (has_beta) y -= sA[n * 64 + lane];
            dp[n * 64 + lane] = y;
            pw[(size_t)n * F + lane] = f2bf(y);
        }
        grid.sync();
    }
}

// ---------------- MFMA projection (unchanged from round 6, verified) -------

__global__ __launch_bounds__(256) void proj_mfma_kernel(
        const u16* __restrict__ projbase, int Rbf, int k0, int kcnt,
        const u16* __restrict__ wtfrag, float* __restrict__ out, int accumulate) {
    int wave = threadIdx.x >> 6;
    int lane = threadIdx.x & 63;
    int n = blockIdx.x * 4 + wave;
    if (n >= N_NODES) return;

    int col = lane & 31;
    int grp = lane >> 5;

    float16 acc = {};
    for (int j = 0; j < kcnt; ++j) {
        int k = k0 + j;
        const u16* Ab = projbase + (size_t)(k % Rbf) * PROJ_ELEMS + (size_t)n * F
                      + (size_t)col * 16 + grp * 8;
        const u16* Bb = wtfrag + (size_t)k * 512 + lane * 8;
        union { uint4 u; short8 s; } av, bv;
        av.u = *(const uint4*)Ab;
        bv.u = *(const uint4*)Bb;
        acc = __builtin_amdgcn_mfma_f32_32x32x16_bf16(av.s, bv.s, acc, 0, 0, 0);
    }

    #pragma unroll
    for (int r = 0; r < 16; ++r) {
        int bt = (r & 3) + 8 * (r >> 2) + 4 * grp;
        float* op = out + ((size_t)bt * N_NODES + n) * C_OUT + col;
        if (accumulate) *op += acc[r];
        else            *op  = acc[r];
    }
}

// ---------------- host launch ----------------

extern "C" void kernel_launch(void* const* d_in, const int* in_sizes, int n_in,
                              void* d_out, int out_size, void* d_ws, size_t ws_size,
                              hipStream_t stream) {
    const float* x    = (const float*)d_in[0];
    const int*   erow = (const int*)  d_in[1];
    const int*   ecol = (const int*)  d_in[2];
    const float* eval = (const float*)d_in[3];
    const float* W    = (const float*)d_in[4];
    float* out = (float*)d_out;

    char* ws = (char*)d_ws;
    size_t o = 0;
    auto alloc = [&](size_t bytes) -> char* {
        o = (o + 511) & ~(size_t)511;
        char* r = ws + o;
        o += bytes;
        return r;
    };
    int*   cnt     = (int*)  alloc((size_t)N_NODES * 4);
    int*   row_ptr = (int*)  alloc((size_t)(N_NODES + 1) * 4);
    int*   cursor  = (int*)  alloc((size_t)N_NODES * 4);
    int*   eidx    = (int*)  alloc((size_t)NNZ_PAD_MAX * 4);
    int2*  cpack   = (int2*) alloc((size_t)NNZ_PAD_MAX * 8);
    u16*   wtfrag  = (u16*)  alloc((size_t)K_S * 512 * 2);
    int*   census  = (int*)  alloc((size_t)MAX_CHUNKS * 8 * 4);

    // fp32 recurrence ring: 3 buffers, sliced layout
    float* fbase = (float*)alloc(3 * BUF_BYTES);

    // bf16 proj ring sized from remaining workspace (round 6 proved Rbf=20 fits)
    o = (o + 511) & ~(size_t)511;
    size_t remain = (ws_size > o) ? (ws_size - o) : 0;
    int Rbf = (int)(remain / PROJ_BYTES);
    if (Rbf > K_S) Rbf = K_S;
    if (Rbf < 3)  Rbf = 3;
    u16* projbase = (u16*)alloc((size_t)Rbf * PROJ_BYTES);

    // CSR build (deterministic, padded) + weight fragments + census zero
    zero_kernel<<<(N_NODES + 255) / 256, 256, 0, stream>>>(cnt, N_NODES);
    zero_kernel<<<(2 * NNZ_PAD_MAX + 255) / 256, 256, 0, stream>>>((int*)cpack, 2 * NNZ_PAD_MAX);
    zero_kernel<<<1, 256, 0, stream>>>(census, MAX_CHUNKS * 8);
    count_kernel<<<(NNZ_E + 255) / 256, 256, 0, stream>>>(erow, cnt);
    scan_kernel<<<1, 256, 0, stream>>>(cnt, row_ptr, cursor);
    scatter_kernel<<<(NNZ_E + 255) / 256, 256, 0, stream>>>(erow, cursor, eidx);
    sort_rows_kernel<<<(N_NODES + 255) / 256, 256, 0, stream>>>(row_ptr, cnt, eidx);
    fill_csr_kernel<<<(N_NODES + 255) / 256, 256, 0, stream>>>(row_ptr, cnt, eidx, ecol, eval, cpack);
    wtfrag_kernel<<<(K_S * 512 + 255) / 256, 256, 0, stream>>>(W, wtfrag);

    // T0 (fp32 sliced) + proj slot 0
    transform_kernel<<<(int)(BUF_FLOATS / 256), 256, 0, stream>>>(x, fbase, projbase);

    // chunks of up to Rbf Chebyshev orders: coop recurrence, then MFMA proj
    const int proj_blocks = (N_NODES + 3) / 4;
    int c0 = 0, chunk_idx = 0;
    while (c0 < K_S) {
        int target = K_S - c0;
        if (target > Rbf) target = Rbf;
        int kb = (c0 == 0) ? 1 : c0;
        int ke = c0 + target;
        if (kb < ke) {
            int* cen = census + chunk_idx * 8;
            void* args[] = { (void*)&fbase, (void*)&projbase, (void*)&Rbf,
                             (void*)&row_ptr, (void*)&cpack, (void*)&cen,
                             (void*)&kb, (void*)&ke };
            hipLaunchCooperativeKernel((void*)cheb_coop_kernel,
                                       dim3(GRID_BLKS), dim3(256), args, 0, stream);
        }
        proj_mfma_kernel<<<proj_blocks, 256, 0, stream>>>(
            projbase, Rbf, c0, target, wtfrag, out, (c0 > 0) ? 1 : 0);
        c0 += target;
        ++chunk_idx;
    }
}

// Round 8
// 750.684 us; speedup vs baseline: 4.8280x; 4.8280x over previous
//
#include <hip/hip_runtime.h>

#define N_NODES 10242
#define NNZ_E   71694
#define NNZ_PAD_MAX (NNZ_E + 7 * N_NODES)   // rows padded to multiple of 8
#define BT      32      // B*T
#define C_IN    16
#define K_S     20
#define C_OUT   32
#define F       512     // BT * C_IN
typedef unsigned short u16;
typedef unsigned int   u32;

#define BUF_FLOATS ((size_t)N_NODES * F)    // fp32 T buffer, layout [n][bt*16+c]
#define BUF_BYTES  (BUF_FLOATS * 4)         // ~21 MB
#define PROJ_ELEMS ((size_t)N_NODES * F)    // bf16 proj copy, layout [n][bt*16+c]
#define PROJ_BYTES (PROJ_ELEMS * 2)         // ~10.5 MB

typedef __attribute__((ext_vector_type(8)))  short short8;
typedef __attribute__((ext_vector_type(16))) float float16;

__device__ __forceinline__ u16 f2bf(float f) {
    union { float f; u32 u; } v; v.f = f;
    u32 r = v.u + 0x7fffu + ((v.u >> 16) & 1u);   // RNE
    return (u16)(r >> 16);
}

// ---------------- CSR build (deterministic, rows padded to x8) -------------

__global__ void zero_kernel(int* p, int n) {
    int i = blockIdx.x * blockDim.x + threadIdx.x;
    if (i < n) p[i] = 0;
}

__global__ void count_kernel(const int* __restrict__ erow, int* cnt) {
    int e = blockIdx.x * blockDim.x + threadIdx.x;
    if (e < NNZ_E) atomicAdd(&cnt[erow[e]], 1);
}

// exclusive scan of PADDED (x8) counts -> row_ptr; cursor = row_ptr
__global__ void scan_kernel(const int* __restrict__ cnt, int* row_ptr, int* cursor) {
    const int T = 256;
    const int chunk = (N_NODES + T - 1) / T;  // 41
    __shared__ int part[T];
    int t = threadIdx.x;
    int base = t * chunk;
    int s = 0;
    for (int i = 0; i < chunk; ++i) {
        int idx = base + i;
        if (idx < N_NODES) s += (cnt[idx] + 7) & ~7;
    }
    part[t] = s;
    __syncthreads();
    for (int off = 1; off < T; off <<= 1) {
        int v = (t >= off) ? part[t - off] : 0;
        __syncthreads();
        part[t] += v;
        __syncthreads();
    }
    int run = (t == 0) ? 0 : part[t - 1];
    for (int i = 0; i < chunk; ++i) {
        int idx = base + i;
        if (idx < N_NODES) {
            row_ptr[idx] = run;
            cursor[idx]  = run;
            run += (cnt[idx] + 7) & ~7;
        }
    }
    if (base <= N_NODES && N_NODES < base + chunk) {
        row_ptr[N_NODES] = run;
    }
}

// scatter ORIGINAL EDGE INDEX (order nondeterministic, fixed by per-row sort)
__global__ void scatter_kernel(const int* __restrict__ erow, int* cursor, int* __restrict__ eidx) {
    int e = blockIdx.x * blockDim.x + threadIdx.x;
    if (e < NNZ_E) {
        int p = atomicAdd(&cursor[erow[e]], 1);
        eidx[p] = e;
    }
}

__global__ void sort_rows_kernel(const int* __restrict__ row_ptr, const int* __restrict__ cnt,
                                 int* eidx) {
    int r = blockIdx.x * blockDim.x + threadIdx.x;
    if (r >= N_NODES) return;
    int s = row_ptr[r], e = s + cnt[r];
    for (int i = s + 1; i < e; ++i) {
        int key = eidx[i];
        int j = i - 1;
        while (j >= s && eidx[j] > key) { eidx[j + 1] = eidx[j]; --j; }
        eidx[j + 1] = key;
    }
}

// fill real edges as packed (col, val); pad slots stay (0, 0.0f) from pre-zero
__global__ void fill_csr_kernel(const int* __restrict__ row_ptr, const int* __restrict__ cnt,
                                const int* __restrict__ eidx,
                                const int* __restrict__ ecol, const float* __restrict__ eval,
                                int2* __restrict__ cpack) {
    int r = blockIdx.x * blockDim.x + threadIdx.x;
    if (r >= N_NODES) return;
    int s = row_ptr[r], e = s + cnt[r];
    for (int p = s; p < e; ++p) {
        int ed = eidx[p];
        cpack[p] = make_int2(ecol[ed], __float_as_int(eval[ed]));
    }
}

// B-fragments for v_mfma_f32_32x32x16_bf16 (verified layout, round 6):
// lane L, reg j -> B[k=8*(L>>5)+j][col=L&31] = W[cout=col][c=k][k_cheb]
__global__ void wtfrag_kernel(const float* __restrict__ W, u16* __restrict__ wtfrag) {
    int i = blockIdx.x * blockDim.x + threadIdx.x;  // K_S*64*8 = 10240
    if (i >= K_S * 64 * 8) return;
    int j    = i & 7;
    int lane = (i >> 3) & 63;
    int k    = i >> 9;
    int cout = lane & 31;
    int c    = ((lane >> 5) << 3) + j;
    wtfrag[i] = f2bf(W[cout * (C_IN * K_S) + c * K_S + k]);
}

// ---------------- transform: x -> T0 (fp32) + bf16 proj copy --------------
// T layout: T[n][bt*16 + c]

__global__ __launch_bounds__(256) void transform_kernel(
        const float* __restrict__ x, float* __restrict__ T0, u16* __restrict__ proj0) {
    int g = blockIdx.x * 256 + threadIdx.x;   // over N*F
    int n   = g >> 9;
    int rem = g & 511;
    int bt  = rem >> 4;
    int c   = rem & 15;
    float v = x[((size_t)bt * N_NODES + n) * C_IN + c];
    T0[(size_t)n * F + rem] = v;
    proj0[(size_t)n * F + rem] = f2bf(v);
}

// ---------------- Chebyshev step: wave-per-node, 8-edge batches ------------
// dst = alpha * L @ srcB + beta * srcA ; projw = bf16(dst)
// 16 independent dwordx4 loads in flight per batch (16 KB/wave) for MLP.

__global__ __launch_bounds__(64) void spmm_step_kernel(
        const float* __restrict__ srcB, const float* __restrict__ srcA,
        float* __restrict__ dst, u16* __restrict__ projw,
        const int* __restrict__ row_ptr, const int2* __restrict__ cpack,
        float alpha, float beta) {
    int n = blockIdx.x;                   // block-uniform -> scalar row_ptr loads
    int lane = threadIdx.x;
    int s = row_ptr[n], e_end = row_ptr[n + 1];   // padded count, multiple of 8
    int o1 = lane * 4;                    // first half of the 512-float row
    int o2 = 256 + lane * 4;              // second half

    float acc1[4] = {0.f, 0.f, 0.f, 0.f};
    float acc2[4] = {0.f, 0.f, 0.f, 0.f};

    for (int e = s; e < e_end; e += 8) {
        int2 p[8];
        #pragma unroll
        for (int j = 0; j < 8; ++j) p[j] = cpack[e + j];
        float4 ba[8], bb[8];
        #pragma unroll
        for (int j = 0; j < 8; ++j) {
            const float* r = srcB + (size_t)p[j].x * F;
            ba[j] = *(const float4*)(r + o1);
            bb[j] = *(const float4*)(r + o2);
        }
        #pragma unroll
        for (int j = 0; j < 8; ++j) {
            float v = __int_as_float(p[j].y);
            acc1[0] += v * ba[j].x; acc1[1] += v * ba[j].y;
            acc1[2] += v * ba[j].z; acc1[3] += v * ba[j].w;
            acc2[0] += v * bb[j].x; acc2[1] += v * bb[j].y;
            acc2[2] += v * bb[j].z; acc2[3] += v * bb[j].w;
        }
    }

    float ya[4], yb[4];
    #pragma unroll
    for (int i = 0; i < 4; ++i) { ya[i] = alpha * acc1[i]; yb[i] = alpha * acc2[i]; }
    if (beta != 0.f) {
        float4 sa = *(const float4*)(srcA + (size_t)n * F + o1);
        float4 sb = *(const float4*)(srcA + (size_t)n * F + o2);
        ya[0] += beta * sa.x; ya[1] += beta * sa.y; ya[2] += beta * sa.z; ya[3] += beta * sa.w;
        yb[0] += beta * sb.x; yb[1] += beta * sb.y; yb[2] += beta * sb.z; yb[3] += beta * sb.w;
    }
    *(float4*)(dst + (size_t)n * F + o1) = *(float4*)ya;
    *(float4*)(dst + (size_t)n * F + o2) = *(float4*)yb;

    u16* pw = projw + (size_t)n * F;
    uint2 pa, pb;
    pa.x = (u32)f2bf(ya[0]) | ((u32)f2bf(ya[1]) << 16);
    pa.y = (u32)f2bf(ya[2]) | ((u32)f2bf(ya[3]) << 16);
    pb.x = (u32)f2bf(yb[0]) | ((u32)f2bf(yb[1]) << 16);
    pb.y = (u32)f2bf(yb[2]) | ((u32)f2bf(yb[3]) << 16);
    *(uint2*)(pw + o1) = pa;
    *(uint2*)(pw + o2) = pb;
}

// ---------------- MFMA projection (verified round 6) -----------------------
// per wave: one node n; tile M=32 (bt) x N=32 (cout), K = kcnt*16.
// A: m=L&31, kk=8*(L>>5)+j ; C/D: col=L&31, row=(reg&3)+8*(reg>>2)+4*(L>>5)

__global__ __launch_bounds__(256) void proj_mfma_kernel(
        const u16* __restrict__ projbase, int Rbf, int k0, int kcnt,
        const u16* __restrict__ wtfrag, float* __restrict__ out, int accumulate) {
    int wave = threadIdx.x >> 6;
    int lane = threadIdx.x & 63;
    int n = blockIdx.x * 4 + wave;
    if (n >= N_NODES) return;

    int col = lane & 31;
    int grp = lane >> 5;

    float16 acc = {};
    for (int j = 0; j < kcnt; ++j) {
        int k = k0 + j;
        const u16* Ab = projbase + (size_t)(k % Rbf) * PROJ_ELEMS + (size_t)n * F
                      + (size_t)col * 16 + grp * 8;
        const u16* Bb = wtfrag + (size_t)k * 512 + lane * 8;
        union { uint4 u; short8 s; } av, bv;
        av.u = *(const uint4*)Ab;
        bv.u = *(const uint4*)Bb;
        acc = __builtin_amdgcn_mfma_f32_32x32x16_bf16(av.s, bv.s, acc, 0, 0, 0);
    }

    #pragma unroll
    for (int r = 0; r < 16; ++r) {
        int bt = (r & 3) + 8 * (r >> 2) + 4 * grp;
        float* op = out + ((size_t)bt * N_NODES + n) * C_OUT + col;
        if (accumulate) *op += acc[r];
        else            *op  = acc[r];
    }
}

// ---------------- host launch ----------------

extern "C" void kernel_launch(void* const* d_in, const int* in_sizes, int n_in,
                              void* d_out, int out_size, void* d_ws, size_t ws_size,
                              hipStream_t stream) {
    const float* x    = (const float*)d_in[0];
    const int*   erow = (const int*)  d_in[1];
    const int*   ecol = (const int*)  d_in[2];
    const float* eval = (const float*)d_in[3];
    const float* W    = (const float*)d_in[4];
    float* out = (float*)d_out;

    char* ws = (char*)d_ws;
    size_t o = 0;
    auto alloc = [&](size_t bytes) -> char* {
        o = (o + 511) & ~(size_t)511;
        char* r = ws + o;
        o += bytes;
        return r;
    };
    int*   cnt     = (int*)  alloc((size_t)N_NODES * 4);
    int*   row_ptr = (int*)  alloc((size_t)(N_NODES + 1) * 4);
    int*   cursor  = (int*)  alloc((size_t)N_NODES * 4);
    int*   eidx    = (int*)  alloc((size_t)NNZ_PAD_MAX * 4);
    int2*  cpack   = (int2*) alloc((size_t)NNZ_PAD_MAX * 8);
    u16*   wtfrag  = (u16*)  alloc((size_t)K_S * 512 * 2);

    // fp32 recurrence ring: 3 buffers
    float* fbase = (float*)alloc(3 * BUF_BYTES);
    auto buf = [&](int k) -> float* { return fbase + (size_t)(k % 3) * BUF_FLOATS; };

    // bf16 proj ring sized from remaining workspace (round 6 proved Rbf=20 fits)
    o = (o + 511) & ~(size_t)511;
    size_t remain = (ws_size > o) ? (ws_size - o) : 0;
    int Rbf = (int)(remain / PROJ_BYTES);
    if (Rbf > K_S) Rbf = K_S;
    if (Rbf < 3)  Rbf = 3;
    u16* projbase = (u16*)alloc((size_t)Rbf * PROJ_BYTES);
    auto projslot = [&](int k) -> u16* { return projbase + (size_t)(k % Rbf) * PROJ_ELEMS; };

    // CSR build (deterministic, padded to x8) + weight fragments
    zero_kernel<<<(N_NODES + 255) / 256, 256, 0, stream>>>(cnt, N_NODES);
    zero_kernel<<<(2 * NNZ_PAD_MAX + 255) / 256, 256, 0, stream>>>((int*)cpack, 2 * NNZ_PAD_MAX);
    count_kernel<<<(NNZ_E + 255) / 256, 256, 0, stream>>>(erow, cnt);
    scan_kernel<<<1, 256, 0, stream>>>(cnt, row_ptr, cursor);
    scatter_kernel<<<(NNZ_E + 255) / 256, 256, 0, stream>>>(erow, cursor, eidx);
    sort_rows_kernel<<<(N_NODES + 255) / 256, 256, 0, stream>>>(row_ptr, cnt, eidx);
    fill_csr_kernel<<<(N_NODES + 255) / 256, 256, 0, stream>>>(row_ptr, cnt, eidx, ecol, eval, cpack);
    wtfrag_kernel<<<(K_S * 512 + 255) / 256, 256, 0, stream>>>(W, wtfrag);

    const int proj_blocks = (N_NODES + 3) / 4;
    int c0 = 0;
    auto maybe_pass = [&](int k_done) {
        int target = K_S - c0;
        if (target > Rbf) target = Rbf;
        if (target > 0 && (k_done - c0 + 1) == target) {
            proj_mfma_kernel<<<proj_blocks, 256, 0, stream>>>(
                projbase, Rbf, c0, target, wtfrag, out, (c0 > 0) ? 1 : 0);
            c0 += target;
        }
    };

    // T0
    transform_kernel<<<(int)(BUF_FLOATS / 256), 256, 0, stream>>>(x, buf(0), projslot(0));
    maybe_pass(0);

    // T1 = L T0 ; Tk = 2 L T_{k-1} - T_{k-2}
    for (int k = 1; k < K_S; ++k) {
        const float* srcB = buf(k - 1);
        const float* srcA = (k >= 2) ? buf(k - 2) : buf(k - 1);  // unread when beta==0
        float alpha = (k == 1) ? 1.f : 2.f;
        float beta  = (k == 1) ? 0.f : -1.f;
        spmm_step_kernel<<<N_NODES, 64, 0, stream>>>(
            srcB, srcA, buf(k), projslot(k), row_ptr, cpack, alpha, beta);
        maybe_pass(k);
    }
}